// Round 1
// baseline (1025.615 us; speedup 1.0000x reference)
//
#include <hip/hip_runtime.h>
#include <cmath>

#define N_AG 2048
#define HID  2048
#define OBSD 1024
#define ACT  64
#define GATES (4*HID)   // 8192
#define KX    (2*HID)   // 4096, X row width = [inp | h]

typedef short s16x8 __attribute__((ext_vector_type(8)));
typedef short s16x4 __attribute__((ext_vector_type(4)));
typedef float f32x4 __attribute__((ext_vector_type(4)));

__device__ __forceinline__ unsigned short f2bf(float f) {
  union { float f; unsigned u; } v; v.f = f;
  return (unsigned short)((v.u + 0x7FFFu + ((v.u >> 16) & 1u)) >> 16);
}
__device__ __forceinline__ float sigm(float x) { return 1.0f / (1.0f + expf(-x)); }

// ---------------- bf16 MFMA GEMM: C(MxN,f32,ldc) = A(MxK,row,lda) * B(NxK,row,ldb)^T
// grid = (N/128, M/128), block = 256 (4 waves, 2x2 wave grid, 64x64 per wave)
__global__ __launch_bounds__(256) void gemm_bt(
    const unsigned short* __restrict__ A, const unsigned short* __restrict__ B,
    float* __restrict__ C, int K, int lda, int ldb, int ldc)
{
  __shared__ __align__(16) unsigned short As[128 * 40];  // +8 pad: 2-way bank alias only (free)
  __shared__ __align__(16) unsigned short Bs[128 * 40];
  const int tid  = threadIdx.x;
  const int lane = tid & 63;
  const int wave = tid >> 6;
  const int wm = wave >> 1, wn = wave & 1;
  const int quad = lane >> 4, l16 = lane & 15;
  const long tileM = (long)blockIdx.y * 128;
  const long tileN = (long)blockIdx.x * 128;

  f32x4 acc[4][4] = {};

  for (int k0 = 0; k0 < K; k0 += 32) {
    // stage 128x32 bf16 tiles of A and B: 512 chunks of 8 elems each, 2 per thread
#pragma unroll
    for (int i = 0; i < 2; ++i) {
      int c  = tid + i * 256;
      int r  = c >> 2, kc = c & 3;
      *(s16x8*)&As[r * 40 + kc * 8] = *(const s16x8*)&A[(tileM + r) * lda + k0 + kc * 8];
      *(s16x8*)&Bs[r * 40 + kc * 8] = *(const s16x8*)&B[(tileN + r) * ldb + k0 + kc * 8];
    }
    __syncthreads();
    s16x8 af[4], bfr[4];
#pragma unroll
    for (int i = 0; i < 4; ++i)
      af[i] = *(const s16x8*)&As[(wm * 64 + i * 16 + l16) * 40 + quad * 8];
#pragma unroll
    for (int j = 0; j < 4; ++j)
      bfr[j] = *(const s16x8*)&Bs[(wn * 64 + j * 16 + l16) * 40 + quad * 8];
#pragma unroll
    for (int i = 0; i < 4; ++i)
#pragma unroll
      for (int j = 0; j < 4; ++j)
        acc[i][j] = __builtin_amdgcn_mfma_f32_16x16x32_bf16(af[i], bfr[j], acc[i][j], 0, 0, 0);
    __syncthreads();
  }
  // epilogue: C/D layout col=lane&15, row=quad*4+reg  [verified m89/m91]
#pragma unroll
  for (int i = 0; i < 4; ++i) {
    long r0 = tileM + wm * 64 + i * 16 + quad * 4;
#pragma unroll
    for (int j = 0; j < 4; ++j) {
      long col = tileN + wn * 64 + j * 16 + l16;
#pragma unroll
      for (int r = 0; r < 4; ++r)
        C[(r0 + r) * ldc + col] = acc[i][j][r];
    }
  }
}

// ---------------- f32 -> bf16 convert (vector x4)
__global__ void cvt4(const float* __restrict__ in, unsigned short* __restrict__ out, int n4) {
  int i = blockIdx.x * 256 + threadIdx.x;
  if (i >= n4) return;
  f32x4 v = ((const f32x4*)in)[i];
  s16x4 o;
  o[0] = (short)f2bf(v[0]); o[1] = (short)f2bf(v[1]);
  o[2] = (short)f2bf(v[2]); o[3] = (short)f2bf(v[3]);
  ((s16x4*)out)[i] = o;
}

// ---------------- build Wc = [w_ih | w_hh] (GATES x KX) in bf16
__global__ void build_wc(const float* __restrict__ w_ih, const float* __restrict__ w_hh,
                         unsigned short* __restrict__ wc) {
  int i = blockIdx.x * 256 + threadIdx.x;          // over GATES*KX/4 = 8388608 chunks
  int k4 = i & 1023;                                // KX/4 chunks per row
  int g  = i >> 10;
  const float* src = (k4 < 512) ? (w_ih + (size_t)g * HID + k4 * 4)
                                : (w_hh + (size_t)g * HID + (k4 - 512) * 4);
  f32x4 v = *(const f32x4*)src;
  s16x4 o;
  o[0] = (short)f2bf(v[0]); o[1] = (short)f2bf(v[1]);
  o[2] = (short)f2bf(v[2]); o[3] = (short)f2bf(v[3]);
  *(s16x4*)&wc[(size_t)g * KX + k4 * 4] = o;
}

// ---------------- n_alive reduction (alive is f32[N_AG])
__global__ void nalive_k(const float* __restrict__ alive, float* __restrict__ nA) {
  __shared__ float red[256];
  float s = 0.f;
  for (int i = threadIdx.x; i < N_AG; i += 256) s += alive[i];
  red[threadIdx.x] = s;
  __syncthreads();
  for (int st = 128; st > 0; st >>= 1) {
    if (threadIdx.x < st) red[threadIdx.x] += red[threadIdx.x + st];
    __syncthreads();
  }
  if (threadIdx.x == 0) nA[0] = red[0];
}

// ---------------- encoder epilogue: e=tanh(z+b); X=[bf16(e) | 0]; cell=0
__global__ void enc_ep(const float* __restrict__ zC, const float* __restrict__ enc_b,
                       float* __restrict__ e, float* __restrict__ cell,
                       unsigned short* __restrict__ X) {
  int i = blockIdx.x * 256 + threadIdx.x;  // over N_AG*HID/4 = 1M
  int n = i >> 9;                          // HID/4=512 chunks per row
  int hid = (i & 511) * 4;
  f32x4 z = ((const f32x4*)zC)[i];
  f32x4 b = *(const f32x4*)&enc_b[hid];
  f32x4 ev; s16x4 xb;
#pragma unroll
  for (int c = 0; c < 4; ++c) { ev[c] = tanhf(z[c] + b[c]); xb[c] = (short)f2bf(ev[c]); }
  ((f32x4*)e)[i] = ev;
  *(s16x4*)&X[(size_t)n * KX + hid] = xb;
  s16x4 zr = {0, 0, 0, 0};
  *(s16x4*)&X[(size_t)n * KX + HID + hid] = zr;
  f32x4 cz = {0.f, 0.f, 0.f, 0.f};
  ((f32x4*)cell)[i] = cz;
}

// ---------------- LSTM pointwise: gate order (i,f,g,o); writes cell,h,X-hpart
__global__ void lstm_k(const float* __restrict__ z, const float* __restrict__ b_ih,
                       const float* __restrict__ b_hh, float* __restrict__ cell,
                       float* __restrict__ h, unsigned short* __restrict__ X) {
  int i = blockIdx.x * 256 + threadIdx.x;  // over 1M
  int n = i >> 9;
  int hid = (i & 511) * 4;
  const float* zr = z + (size_t)n * GATES;
  f32x4 zi = *(const f32x4*)&zr[hid];
  f32x4 zf = *(const f32x4*)&zr[HID + hid];
  f32x4 zg = *(const f32x4*)&zr[2 * HID + hid];
  f32x4 zo = *(const f32x4*)&zr[3 * HID + hid];
  f32x4 bi = *(const f32x4*)&b_ih[hid];          f32x4 ci_ = *(const f32x4*)&b_hh[hid];
  f32x4 bf_ = *(const f32x4*)&b_ih[HID + hid];   f32x4 cf = *(const f32x4*)&b_hh[HID + hid];
  f32x4 bg = *(const f32x4*)&b_ih[2 * HID + hid]; f32x4 cg = *(const f32x4*)&b_hh[2 * HID + hid];
  f32x4 bo = *(const f32x4*)&b_ih[3 * HID + hid]; f32x4 co = *(const f32x4*)&b_hh[3 * HID + hid];
  f32x4 cold = ((const f32x4*)cell)[i];
  f32x4 cnew, hv; s16x4 xb;
#pragma unroll
  for (int c = 0; c < 4; ++c) {
    float ig = sigm(zi[c] + bi[c] + ci_[c]);
    float fg = sigm(zf[c] + bf_[c] + cf[c]);
    float gg = tanhf(zg[c] + bg[c] + cg[c]);
    float og = sigm(zo[c] + bo[c] + co[c]);
    cnew[c] = fg * cold[c] + ig * gg;
    hv[c] = og * tanhf(cnew[c]);
    xb[c] = (short)f2bf(hv[c]);
  }
  ((f32x4*)cell)[i] = cnew;
  ((f32x4*)h)[i] = hv;
  *(s16x4*)&X[(size_t)n * KX + HID + hid] = xb;
}

// ---------------- column sum: S[hid] = sum_n alive[n]*h[n][hid]  (S pre-zeroed)
__global__ void colsum(const float* __restrict__ h, const float* __restrict__ alive,
                       float* __restrict__ S) {
  int hid = blockIdx.x * 256 + threadIdx.x;
  int r0 = blockIdx.y * 128;
  float s = 0.f;
  for (int n = r0; n < r0 + 128; ++n) s += alive[n] * h[(size_t)n * HID + hid];
  atomicAdd(&S[hid], s);
}

// ---------------- comm + inp: X-inp-part = bf16(e + alive_i*(S - alive_i*h)/ (nA-1))
__global__ void inp_k(const float* __restrict__ e, const float* __restrict__ h,
                      const float* __restrict__ S, const float* __restrict__ alive,
                      const float* __restrict__ nA, unsigned short* __restrict__ X) {
  int i = blockIdx.x * 256 + threadIdx.x;  // over 1M
  int n = i >> 9;
  int hid = (i & 511) * 4;
  f32x4 ev = ((const f32x4*)e)[i];
  f32x4 hv = ((const f32x4*)h)[i];
  f32x4 Sv = *(const f32x4*)&S[hid];
  float al = alive[n];
  float inv = al / (nA[0] - 1.0f);
  s16x4 xb;
#pragma unroll
  for (int c = 0; c < 4; ++c) {
    float x = ev[c] + (Sv[c] - al * hv[c]) * inv;
    xb[c] = (short)f2bf(x);
  }
  *(s16x4*)&X[(size_t)n * KX + hid] = xb;
}

// ---------------- head: log_softmax(h@act_w^T + act_b) and h@val_w^T + val_b
__global__ __launch_bounds__(64) void head_k(const float* __restrict__ h,
                                             const float* __restrict__ act_w,
                                             const float* __restrict__ act_b,
                                             const float* __restrict__ val_w,
                                             const float* __restrict__ val_b,
                                             float* __restrict__ out) {
  __shared__ float hrow[HID];
  int n = blockIdx.x, t = threadIdx.x;  // 64 threads = 1 wave
  const float* hr = h + (size_t)n * HID;
  for (int k = t; k < HID; k += 64) hrow[k] = hr[k];
  __syncthreads();
  const float* aw = act_w + (size_t)t * HID;
  float acc = act_b[t];
  for (int k = 0; k < HID; k += 4) {
    f32x4 a = *(const f32x4*)&aw[k];
    f32x4 hh = *(const f32x4*)&hrow[k];
    acc += a[0] * hh[0] + a[1] * hh[1] + a[2] * hh[2] + a[3] * hh[3];
  }
  float m = acc;
  for (int off = 32; off; off >>= 1) m = fmaxf(m, __shfl_xor(m, off));
  float ex = expf(acc - m), s = ex;
  for (int off = 32; off; off >>= 1) s += __shfl_xor(s, off);
  out[(size_t)n * ACT + t] = acc - m - logf(s);
  float vp = 0.f;
  for (int k = t; k < HID; k += 64) vp += hrow[k] * val_w[k];
  for (int off = 32; off; off >>= 1) vp += __shfl_xor(vp, off);
  if (t == 0) out[(size_t)N_AG * ACT + n] = vp + val_b[0];
}

extern "C" void kernel_launch(void* const* d_in, const int* in_sizes, int n_in,
                              void* d_out, int out_size, void* d_ws, size_t ws_size,
                              hipStream_t stream) {
  const float* obs   = (const float*)d_in[0];
  const float* alive = (const float*)d_in[1];
  const float* enc_w = (const float*)d_in[2];
  const float* enc_b = (const float*)d_in[3];
  // d_in[4] g_w, d_in[5] g_b: unused — gate = ceil(sigmoid(.)) == 1 identically
  const float* w_ih  = (const float*)d_in[6];
  const float* w_hh  = (const float*)d_in[7];
  const float* b_ih  = (const float*)d_in[8];
  const float* b_hh  = (const float*)d_in[9];
  const float* act_w = (const float*)d_in[10];
  const float* act_b = (const float*)d_in[11];
  const float* val_w = (const float*)d_in[12];
  const float* val_b = (const float*)d_in[13];
  float* out = (float*)d_out;

  char* p = (char*)d_ws;
  unsigned short* Wc   = (unsigned short*)p; p += (size_t)GATES * KX * 2;   // 64 MB
  unsigned short* X    = (unsigned short*)p; p += (size_t)N_AG * KX * 2;    // 16 MB
  unsigned short* obsb = (unsigned short*)p; p += (size_t)N_AG * OBSD * 2;  // 4 MB
  unsigned short* encb = (unsigned short*)p; p += (size_t)HID * OBSD * 2;   // 4 MB
  float* z    = (float*)p; p += (size_t)N_AG * GATES * 4;                   // 64 MB
  float* e    = (float*)p; p += (size_t)N_AG * HID * 4;                     // 16 MB
  float* h    = (float*)p; p += (size_t)N_AG * HID * 4;
  float* cell = (float*)p; p += (size_t)N_AG * HID * 4;
  float* S    = (float*)p; p += 2048 * 4;
  float* nA   = (float*)p; p += 256;

  // per-launch input conversion (ws is re-poisoned every call)
  cvt4<<<(N_AG * OBSD / 4 + 255) / 256, 256, 0, stream>>>(obs, obsb, N_AG * OBSD / 4);
  cvt4<<<(HID * OBSD / 4 + 255) / 256, 256, 0, stream>>>(enc_w, encb, HID * OBSD / 4);
  build_wc<<<(GATES * KX / 4) / 256, 256, 0, stream>>>(w_ih, w_hh, Wc);
  nalive_k<<<1, 256, 0, stream>>>(alive, nA);

  // encoder: z(2048x2048) = obs @ enc_w^T, then e = tanh(z + b)
  gemm_bt<<<dim3(HID / 128, N_AG / 128), 256, 0, stream>>>(obsb, encb, z, OBSD, OBSD, OBSD, HID);
  enc_ep<<<(N_AG * HID / 4) / 256, 256, 0, stream>>>(z, enc_b, e, cell, X);

  for (int it = 0; it < 3; ++it) {
    if (it > 0) {
      hipMemsetAsync(S, 0, 2048 * 4, stream);
      colsum<<<dim3(HID / 256, 16), 256, 0, stream>>>(h, alive, S);
      inp_k<<<(N_AG * HID / 4) / 256, 256, 0, stream>>>(e, h, S, alive, nA, X);
    }
    // z(2048x8192) = X @ Wc^T ; iter0: h==0 so only K=HID (inp half)
    int K = (it == 0) ? HID : KX;
    gemm_bt<<<dim3(GATES / 128, N_AG / 128), 256, 0, stream>>>(X, Wc, z, K, KX, KX, GATES);
    lstm_k<<<(N_AG * HID / 4) / 256, 256, 0, stream>>>(z, b_ih, b_hh, cell, h, X);
  }

  head_k<<<N_AG, 64, 0, stream>>>(h, act_w, act_b, val_w, val_b, out);
}

// Round 2
// 974.041 us; speedup vs baseline: 1.0529x; 1.0529x over previous
//
#include <hip/hip_runtime.h>
#include <cmath>

#define N_AG 2048
#define HID  2048
#define OBSD 1024
#define ACT  64
#define GATES (4*HID)   // 8192
#define KX    (2*HID)   // 4096, X row width = [inp | h]

typedef short s16x8 __attribute__((ext_vector_type(8)));
typedef short s16x4 __attribute__((ext_vector_type(4)));
typedef float f32x4 __attribute__((ext_vector_type(4)));

__device__ __forceinline__ unsigned short f2bf(float f) {
  union { float f; unsigned u; } v; v.f = f;
  return (unsigned short)((v.u + 0x7FFFu + ((v.u >> 16) & 1u)) >> 16);
}
__device__ __forceinline__ float sigm(float x) { return 1.0f / (1.0f + expf(-x)); }

// async global->LDS DMA, 16B per lane; LDS dest = wave-uniform base + lane*16
__device__ __forceinline__ void gload16(const unsigned short* g, unsigned short* l) {
  __builtin_amdgcn_global_load_lds(
      (const __attribute__((address_space(1))) void*)g,
      (__attribute__((address_space(3))) void*)l, 16, 0, 0);
}

// ---------------- bf16 MFMA GEMM: C(MxN,f32,ldc) = A(MxK,row,lda) * B(NxK,row,ldb)^T
// grid = (N/128, M/128), block = 256 (4 waves, 2x2 wave grid, 64x64 per wave)
// m97-pattern: global_load_lds width=16 staging into UNPADDED row-major LDS tiles.
__global__ __launch_bounds__(256) void gemm_bt(
    const unsigned short* __restrict__ A, const unsigned short* __restrict__ B,
    float* __restrict__ C, int K, int lda, int ldb, int ldc)
{
  __shared__ __align__(16) unsigned short As[128 * 32];  // 8 KB, NO pad (DMA constraint)
  __shared__ __align__(16) unsigned short Bs[128 * 32];
  const int tid  = threadIdx.x;
  const int lane = tid & 63;
  const int wave = tid >> 6;
  const int wm = wave >> 1, wn = wave & 1;
  const int quad = lane >> 4, l16 = lane & 15;
  const long tileM = (long)blockIdx.y * 128;
  const long tileN = (long)blockIdx.x * 128;

  // staging map: wave owns rows [wave*32, wave*32+32), 2 issues x 16 rows;
  // lane i -> row (i>>2), 16B chunk (i&3). LDS lands row-major stride 32.
  const int srow = lane >> 2;           // 0..15
  const int skc  = (lane & 3) * 8;      // elem offset of 16B chunk

  f32x4 acc[4][4] = {};

  for (int k0 = 0; k0 < K; k0 += 32) {
#pragma unroll
    for (int t = 0; t < 2; ++t) {
      int r = wave * 32 + t * 16;
      gload16(&A[(tileM + r + srow) * lda + k0 + skc], &As[r * 32]);
      gload16(&B[(tileN + r + srow) * ldb + k0 + skc], &Bs[r * 32]);
    }
    __syncthreads();
    s16x8 af[4], bfr[4];
#pragma unroll
    for (int i = 0; i < 4; ++i)
      af[i] = *(const s16x8*)&As[(wm * 64 + i * 16 + l16) * 32 + quad * 8];
#pragma unroll
    for (int j = 0; j < 4; ++j)
      bfr[j] = *(const s16x8*)&Bs[(wn * 64 + j * 16 + l16) * 32 + quad * 8];
#pragma unroll
    for (int i = 0; i < 4; ++i)
#pragma unroll
      for (int j = 0; j < 4; ++j)
        acc[i][j] = __builtin_amdgcn_mfma_f32_16x16x32_bf16(af[i], bfr[j], acc[i][j], 0, 0, 0);
    __syncthreads();
  }
  // epilogue: C/D layout col=lane&15, row=quad*4+reg  [verified m89/m91]
#pragma unroll
  for (int i = 0; i < 4; ++i) {
    long r0 = tileM + wm * 64 + i * 16 + quad * 4;
#pragma unroll
    for (int j = 0; j < 4; ++j) {
      long col = tileN + wn * 64 + j * 16 + l16;
#pragma unroll
      for (int r = 0; r < 4; ++r)
        C[(r0 + r) * ldc + col] = acc[i][j][r];
    }
  }
}

// ---------------- f32 -> bf16 convert (vector x4)
__global__ void cvt4(const float* __restrict__ in, unsigned short* __restrict__ out, int n4) {
  int i = blockIdx.x * 256 + threadIdx.x;
  if (i >= n4) return;
  f32x4 v = ((const f32x4*)in)[i];
  s16x4 o;
  o[0] = (short)f2bf(v[0]); o[1] = (short)f2bf(v[1]);
  o[2] = (short)f2bf(v[2]); o[3] = (short)f2bf(v[3]);
  ((s16x4*)out)[i] = o;
}

// ---------------- build Wc = [w_ih | w_hh] (GATES x KX) in bf16
__global__ void build_wc(const float* __restrict__ w_ih, const float* __restrict__ w_hh,
                         unsigned short* __restrict__ wc) {
  int i = blockIdx.x * 256 + threadIdx.x;          // over GATES*KX/4 = 8388608 chunks
  int k4 = i & 1023;                                // KX/4 chunks per row
  int g  = i >> 10;
  const float* src = (k4 < 512) ? (w_ih + (size_t)g * HID + k4 * 4)
                                : (w_hh + (size_t)g * HID + (k4 - 512) * 4);
  f32x4 v = *(const f32x4*)src;
  s16x4 o;
  o[0] = (short)f2bf(v[0]); o[1] = (short)f2bf(v[1]);
  o[2] = (short)f2bf(v[2]); o[3] = (short)f2bf(v[3]);
  *(s16x4*)&wc[(size_t)g * KX + k4 * 4] = o;
}

// ---------------- n_alive reduction (alive is f32[N_AG])
__global__ void nalive_k(const float* __restrict__ alive, float* __restrict__ nA) {
  __shared__ float red[256];
  float s = 0.f;
  for (int i = threadIdx.x; i < N_AG; i += 256) s += alive[i];
  red[threadIdx.x] = s;
  __syncthreads();
  for (int st = 128; st > 0; st >>= 1) {
    if (threadIdx.x < st) red[threadIdx.x] += red[threadIdx.x + st];
    __syncthreads();
  }
  if (threadIdx.x == 0) nA[0] = red[0];
}

// ---------------- encoder epilogue: e=tanh(z+b); X=[bf16(e) | 0]; cell=0
__global__ void enc_ep(const float* __restrict__ zC, const float* __restrict__ enc_b,
                       float* __restrict__ e, float* __restrict__ cell,
                       unsigned short* __restrict__ X) {
  int i = blockIdx.x * 256 + threadIdx.x;  // over N_AG*HID/4 = 1M
  int n = i >> 9;                          // HID/4=512 chunks per row
  int hid = (i & 511) * 4;
  f32x4 z = ((const f32x4*)zC)[i];
  f32x4 b = *(const f32x4*)&enc_b[hid];
  f32x4 ev; s16x4 xb;
#pragma unroll
  for (int c = 0; c < 4; ++c) { ev[c] = tanhf(z[c] + b[c]); xb[c] = (short)f2bf(ev[c]); }
  ((f32x4*)e)[i] = ev;
  *(s16x4*)&X[(size_t)n * KX + hid] = xb;
  s16x4 zr = {0, 0, 0, 0};
  *(s16x4*)&X[(size_t)n * KX + HID + hid] = zr;
  f32x4 cz = {0.f, 0.f, 0.f, 0.f};
  ((f32x4*)cell)[i] = cz;
}

// ---------------- LSTM pointwise: gate order (i,f,g,o); writes cell,h,X-hpart
__global__ void lstm_k(const float* __restrict__ z, const float* __restrict__ b_ih,
                       const float* __restrict__ b_hh, float* __restrict__ cell,
                       float* __restrict__ h, unsigned short* __restrict__ X) {
  int i = blockIdx.x * 256 + threadIdx.x;  // over 1M
  int n = i >> 9;
  int hid = (i & 511) * 4;
  const float* zr = z + (size_t)n * GATES;
  f32x4 zi = *(const f32x4*)&zr[hid];
  f32x4 zf = *(const f32x4*)&zr[HID + hid];
  f32x4 zg = *(const f32x4*)&zr[2 * HID + hid];
  f32x4 zo = *(const f32x4*)&zr[3 * HID + hid];
  f32x4 bi = *(const f32x4*)&b_ih[hid];          f32x4 ci_ = *(const f32x4*)&b_hh[hid];
  f32x4 bf_ = *(const f32x4*)&b_ih[HID + hid];   f32x4 cf = *(const f32x4*)&b_hh[HID + hid];
  f32x4 bg = *(const f32x4*)&b_ih[2 * HID + hid]; f32x4 cg = *(const f32x4*)&b_hh[2 * HID + hid];
  f32x4 bo = *(const f32x4*)&b_ih[3 * HID + hid]; f32x4 co = *(const f32x4*)&b_hh[3 * HID + hid];
  f32x4 cold = ((const f32x4*)cell)[i];
  f32x4 cnew, hv; s16x4 xb;
#pragma unroll
  for (int c = 0; c < 4; ++c) {
    float ig = sigm(zi[c] + bi[c] + ci_[c]);
    float fg = sigm(zf[c] + bf_[c] + cf[c]);
    float gg = tanhf(zg[c] + bg[c] + cg[c]);
    float og = sigm(zo[c] + bo[c] + co[c]);
    cnew[c] = fg * cold[c] + ig * gg;
    hv[c] = og * tanhf(cnew[c]);
    xb[c] = (short)f2bf(hv[c]);
  }
  ((f32x4*)cell)[i] = cnew;
  ((f32x4*)h)[i] = hv;
  *(s16x4*)&X[(size_t)n * KX + HID + hid] = xb;
}

// ---------------- column sum: S[hid] = sum_n alive[n]*h[n][hid]  (S pre-zeroed)
__global__ void colsum(const float* __restrict__ h, const float* __restrict__ alive,
                       float* __restrict__ S) {
  int hid = blockIdx.x * 256 + threadIdx.x;
  int r0 = blockIdx.y * 128;
  float s = 0.f;
  for (int n = r0; n < r0 + 128; ++n) s += alive[n] * h[(size_t)n * HID + hid];
  atomicAdd(&S[hid], s);
}

// ---------------- comm + inp: X-inp-part = bf16(e + alive_i*(S - alive_i*h)/ (nA-1))
__global__ void inp_k(const float* __restrict__ e, const float* __restrict__ h,
                      const float* __restrict__ S, const float* __restrict__ alive,
                      const float* __restrict__ nA, unsigned short* __restrict__ X) {
  int i = blockIdx.x * 256 + threadIdx.x;  // over 1M
  int n = i >> 9;
  int hid = (i & 511) * 4;
  f32x4 ev = ((const f32x4*)e)[i];
  f32x4 hv = ((const f32x4*)h)[i];
  f32x4 Sv = *(const f32x4*)&S[hid];
  float al = alive[n];
  float inv = al / (nA[0] - 1.0f);
  s16x4 xb;
#pragma unroll
  for (int c = 0; c < 4; ++c) {
    float x = ev[c] + (Sv[c] - al * hv[c]) * inv;
    xb[c] = (short)f2bf(x);
  }
  *(s16x4*)&X[(size_t)n * KX + hid] = xb;
}

// ---------------- head: log_softmax(h@act_w^T + act_b) and h@val_w^T + val_b
__global__ __launch_bounds__(64) void head_k(const float* __restrict__ h,
                                             const float* __restrict__ act_w,
                                             const float* __restrict__ act_b,
                                             const float* __restrict__ val_w,
                                             const float* __restrict__ val_b,
                                             float* __restrict__ out) {
  __shared__ float hrow[HID];
  int n = blockIdx.x, t = threadIdx.x;  // 64 threads = 1 wave
  const float* hr = h + (size_t)n * HID;
  for (int k = t; k < HID; k += 64) hrow[k] = hr[k];
  __syncthreads();
  const float* aw = act_w + (size_t)t * HID;
  float acc = act_b[t];
  for (int k = 0; k < HID; k += 4) {
    f32x4 a = *(const f32x4*)&aw[k];
    f32x4 hh = *(const f32x4*)&hrow[k];
    acc += a[0] * hh[0] + a[1] * hh[1] + a[2] * hh[2] + a[3] * hh[3];
  }
  float m = acc;
  for (int off = 32; off; off >>= 1) m = fmaxf(m, __shfl_xor(m, off));
  float ex = expf(acc - m), s = ex;
  for (int off = 32; off; off >>= 1) s += __shfl_xor(s, off);
  out[(size_t)n * ACT + t] = acc - m - logf(s);
  float vp = 0.f;
  for (int k = t; k < HID; k += 64) vp += hrow[k] * val_w[k];
  for (int off = 32; off; off >>= 1) vp += __shfl_xor(vp, off);
  if (t == 0) out[(size_t)N_AG * ACT + n] = vp + val_b[0];
}

extern "C" void kernel_launch(void* const* d_in, const int* in_sizes, int n_in,
                              void* d_out, int out_size, void* d_ws, size_t ws_size,
                              hipStream_t stream) {
  const float* obs   = (const float*)d_in[0];
  const float* alive = (const float*)d_in[1];
  const float* enc_w = (const float*)d_in[2];
  const float* enc_b = (const float*)d_in[3];
  // d_in[4] g_w, d_in[5] g_b: unused — gate = ceil(sigmoid(.)) == 1 identically
  const float* w_ih  = (const float*)d_in[6];
  const float* w_hh  = (const float*)d_in[7];
  const float* b_ih  = (const float*)d_in[8];
  const float* b_hh  = (const float*)d_in[9];
  const float* act_w = (const float*)d_in[10];
  const float* act_b = (const float*)d_in[11];
  const float* val_w = (const float*)d_in[12];
  const float* val_b = (const float*)d_in[13];
  float* out = (float*)d_out;

  char* p = (char*)d_ws;
  unsigned short* Wc   = (unsigned short*)p; p += (size_t)GATES * KX * 2;   // 64 MB
  unsigned short* X    = (unsigned short*)p; p += (size_t)N_AG * KX * 2;    // 16 MB
  unsigned short* obsb = (unsigned short*)p; p += (size_t)N_AG * OBSD * 2;  // 4 MB
  unsigned short* encb = (unsigned short*)p; p += (size_t)HID * OBSD * 2;   // 4 MB
  float* z    = (float*)p; p += (size_t)N_AG * GATES * 4;                   // 64 MB
  float* e    = (float*)p; p += (size_t)N_AG * HID * 4;                     // 16 MB
  float* h    = (float*)p; p += (size_t)N_AG * HID * 4;
  float* cell = (float*)p; p += (size_t)N_AG * HID * 4;
  float* S    = (float*)p; p += 2048 * 4;
  float* nA   = (float*)p; p += 256;

  // per-launch input conversion (ws is re-poisoned every call)
  cvt4<<<(N_AG * OBSD / 4 + 255) / 256, 256, 0, stream>>>(obs, obsb, N_AG * OBSD / 4);
  cvt4<<<(HID * OBSD / 4 + 255) / 256, 256, 0, stream>>>(enc_w, encb, HID * OBSD / 4);
  build_wc<<<(GATES * KX / 4) / 256, 256, 0, stream>>>(w_ih, w_hh, Wc);
  nalive_k<<<1, 256, 0, stream>>>(alive, nA);

  // encoder: z(2048x2048) = obs @ enc_w^T, then e = tanh(z + b)
  gemm_bt<<<dim3(HID / 128, N_AG / 128), 256, 0, stream>>>(obsb, encb, z, OBSD, OBSD, OBSD, HID);
  enc_ep<<<(N_AG * HID / 4) / 256, 256, 0, stream>>>(z, enc_b, e, cell, X);

  for (int it = 0; it < 3; ++it) {
    if (it > 0) {
      hipMemsetAsync(S, 0, 2048 * 4, stream);
      colsum<<<dim3(HID / 256, 16), 256, 0, stream>>>(h, alive, S);
      inp_k<<<(N_AG * HID / 4) / 256, 256, 0, stream>>>(e, h, S, alive, nA, X);
    }
    // z(2048x8192) = X @ Wc^T ; iter0: h==0 so only K=HID (inp half)
    int K = (it == 0) ? HID : KX;
    gemm_bt<<<dim3(GATES / 128, N_AG / 128), 256, 0, stream>>>(X, Wc, z, K, KX, KX, GATES);
    lstm_k<<<(N_AG * HID / 4) / 256, 256, 0, stream>>>(z, b_ih, b_hh, cell, h, X);
  }

  head_k<<<N_AG, 64, 0, stream>>>(h, act_w, act_b, val_w, val_b, out);
}

// Round 3
// 810.722 us; speedup vs baseline: 1.2651x; 1.2014x over previous
//
#include <hip/hip_runtime.h>
#include <cmath>

#define N_AG 2048
#define HID  2048
#define OBSD 1024
#define ACT  64
#define GATES (4*HID)   // 8192
#define KX    (2*HID)   // 4096, X row width = [inp | h]

typedef short s16x8 __attribute__((ext_vector_type(8)));
typedef short s16x4 __attribute__((ext_vector_type(4)));
typedef float f32x4 __attribute__((ext_vector_type(4)));

__device__ __forceinline__ unsigned short f2bf(float f) {
  union { float f; unsigned u; } v; v.f = f;
  return (unsigned short)((v.u + 0x7FFFu + ((v.u >> 16) & 1u)) >> 16);
}
__device__ __forceinline__ float sigm(float x) { return 1.0f / (1.0f + expf(-x)); }

// async global->LDS DMA, 16B per lane; LDS dest = wave-uniform base + lane*16
__device__ __forceinline__ void gload16(const unsigned short* g, unsigned short* l) {
  __builtin_amdgcn_global_load_lds(
      (const __attribute__((address_space(1))) void*)g,
      (__attribute__((address_space(3))) void*)l, 16, 0, 0);
}

// ---------------- bf16 MFMA GEMM: C(MxN,f32,ldc) = A(MxK,row,lda) * B(NxK,row,ldb)^T
// grid = (N/128, M/128), block = 256 (4 waves, 2x2 wave grid, 64x64 per wave).
// Double-buffered global_load_lds pipeline, ONE barrier per K-iter:
//   sync(i) drains DMA(tile i) issued one full MFMA-phase earlier -> latency hidden.
// MODE 0: C = A*B^T (f32 store). MODE 1: encoder epilogue e=tanh(C+bias),
//   writes e (f32), X[:,0:HID]=bf16(e), X[:,HID:2H]=0.
template <int MODE>
__global__ __launch_bounds__(256) void gemm_bt(
    const unsigned short* __restrict__ A, const unsigned short* __restrict__ B,
    float* __restrict__ C, int K, int lda, int ldb, int ldc,
    const float* __restrict__ bias, unsigned short* __restrict__ X)
{
  __shared__ __align__(16) unsigned short As[2][128 * 32];  // unpadded (DMA constraint)
  __shared__ __align__(16) unsigned short Bs[2][128 * 32];
  const int tid  = threadIdx.x;
  const int lane = tid & 63;
  const int wave = tid >> 6;
  const int wm = wave >> 1, wn = wave & 1;
  const int quad = lane >> 4, l16 = lane & 15;
  const long tileM = (long)blockIdx.y * 128;
  const long tileN = (long)blockIdx.x * 128;

  // staging: wave owns rows [wave*32, wave*32+32), 2 issues x 16 rows;
  // lane -> row (lane>>2), 16B chunk (lane&3). LDS row-major stride 32.
  const int srow = lane >> 2;
  const int skc  = (lane & 3) * 8;
  const unsigned short* gA = &A[(tileM + wave * 32 + srow) * lda + skc];
  const unsigned short* gB = &B[(tileN + wave * 32 + srow) * ldb + skc];
  const int ldsOff = wave * 32 * 32;  // elem offset of wave's 32-row chunk

  f32x4 acc[4][4] = {};
  const int nIt = K >> 5;

  // prefetch tile 0 -> buf 0
  gload16(gA, &As[0][ldsOff]);
  gload16(gA + 16 * lda, &As[0][ldsOff + 16 * 32]);
  gload16(gB, &Bs[0][ldsOff]);
  gload16(gB + 16 * ldb, &Bs[0][ldsOff + 16 * 32]);

  for (int i = 0; i < nIt; ++i) {
    __syncthreads();  // vmcnt(0) drain: DMA(tile i) complete; buf(i&1) reads of i-2 done
    if (i + 1 < nIt) {
      const int nb = (i + 1) & 1;
      const long ko = (long)(i + 1) * 32;
      gload16(gA + ko, &As[nb][ldsOff]);
      gload16(gA + ko + 16 * lda, &As[nb][ldsOff + 16 * 32]);
      gload16(gB + ko, &Bs[nb][ldsOff]);
      gload16(gB + ko + 16 * ldb, &Bs[nb][ldsOff + 16 * 32]);
    }
    const unsigned short* as = As[i & 1];
    const unsigned short* bs = Bs[i & 1];
    s16x8 af[4], bfr[4];
#pragma unroll
    for (int ii = 0; ii < 4; ++ii)
      af[ii] = *(const s16x8*)&as[(wm * 64 + ii * 16 + l16) * 32 + quad * 8];
#pragma unroll
    for (int j = 0; j < 4; ++j)
      bfr[j] = *(const s16x8*)&bs[(wn * 64 + j * 16 + l16) * 32 + quad * 8];
#pragma unroll
    for (int ii = 0; ii < 4; ++ii)
#pragma unroll
      for (int j = 0; j < 4; ++j)
        acc[ii][j] = __builtin_amdgcn_mfma_f32_16x16x32_bf16(af[ii], bfr[j], acc[ii][j], 0, 0, 0);
  }
  // epilogue: C/D layout col=lane&15, row=quad*4+reg  [verified m89/m91]
#pragma unroll
  for (int i = 0; i < 4; ++i) {
    long r0 = tileM + wm * 64 + i * 16 + quad * 4;
#pragma unroll
    for (int j = 0; j < 4; ++j) {
      long col = tileN + wn * 64 + j * 16 + l16;
      if (MODE == 0) {
#pragma unroll
        for (int r = 0; r < 4; ++r)
          C[(r0 + r) * ldc + col] = acc[i][j][r];
      } else {
        float bv = bias[col];
#pragma unroll
        for (int r = 0; r < 4; ++r) {
          float ev = tanhf(acc[i][j][r] + bv);
          long row = r0 + r;
          C[row * ldc + col] = ev;                       // e (f32)
          X[row * KX + col] = f2bf(ev);                  // X inp-half
          X[row * KX + HID + col] = 0;                   // X h-half = 0
        }
      }
    }
  }
}

// ---------------- f32 -> bf16 convert (vector x4)
__global__ void cvt4(const float* __restrict__ in, unsigned short* __restrict__ out, int n4) {
  int i = blockIdx.x * 256 + threadIdx.x;
  if (i >= n4) return;
  f32x4 v = ((const f32x4*)in)[i];
  s16x4 o;
  o[0] = (short)f2bf(v[0]); o[1] = (short)f2bf(v[1]);
  o[2] = (short)f2bf(v[2]); o[3] = (short)f2bf(v[3]);
  ((s16x4*)out)[i] = o;
}

// ---------------- build Wc = [w_ih | w_hh] (GATES x KX) in bf16
__global__ void build_wc(const float* __restrict__ w_ih, const float* __restrict__ w_hh,
                         unsigned short* __restrict__ wc) {
  int i = blockIdx.x * 256 + threadIdx.x;          // over GATES*KX/4 chunks
  int k4 = i & 1023;                                // KX/4 chunks per row
  int g  = i >> 10;
  const float* src = (k4 < 512) ? (w_ih + (size_t)g * HID + k4 * 4)
                                : (w_hh + (size_t)g * HID + (k4 - 512) * 4);
  f32x4 v = *(const f32x4*)src;
  s16x4 o;
  o[0] = (short)f2bf(v[0]); o[1] = (short)f2bf(v[1]);
  o[2] = (short)f2bf(v[2]); o[3] = (short)f2bf(v[3]);
  *(s16x4*)&wc[(size_t)g * KX + k4 * 4] = o;
}

// ---------------- n_alive reduction (alive is f32[N_AG])
__global__ void nalive_k(const float* __restrict__ alive, float* __restrict__ nA) {
  __shared__ float red[256];
  float s = 0.f;
  for (int i = threadIdx.x; i < N_AG; i += 256) s += alive[i];
  red[threadIdx.x] = s;
  __syncthreads();
  for (int st = 128; st > 0; st >>= 1) {
    if (threadIdx.x < st) red[threadIdx.x] += red[threadIdx.x + st];
    __syncthreads();
  }
  if (threadIdx.x == 0) nA[0] = red[0];
}

// ---------------- LSTM pointwise: gate order (i,f,g,o); writes cell,h,X-hpart
__global__ void lstm_k(const float* __restrict__ z, const float* __restrict__ b_ih,
                       const float* __restrict__ b_hh, float* __restrict__ cell,
                       float* __restrict__ h, unsigned short* __restrict__ X, int first) {
  int i = blockIdx.x * 256 + threadIdx.x;  // over 1M
  int n = i >> 9;
  int hid = (i & 511) * 4;
  const float* zr = z + (size_t)n * GATES;
  f32x4 zi = *(const f32x4*)&zr[hid];
  f32x4 zf = *(const f32x4*)&zr[HID + hid];
  f32x4 zg = *(const f32x4*)&zr[2 * HID + hid];
  f32x4 zo = *(const f32x4*)&zr[3 * HID + hid];
  f32x4 bi = *(const f32x4*)&b_ih[hid];           f32x4 ci_ = *(const f32x4*)&b_hh[hid];
  f32x4 bf_ = *(const f32x4*)&b_ih[HID + hid];    f32x4 cf = *(const f32x4*)&b_hh[HID + hid];
  f32x4 bg = *(const f32x4*)&b_ih[2 * HID + hid]; f32x4 cg = *(const f32x4*)&b_hh[2 * HID + hid];
  f32x4 bo = *(const f32x4*)&b_ih[3 * HID + hid]; f32x4 co = *(const f32x4*)&b_hh[3 * HID + hid];
  f32x4 cold = {0.f, 0.f, 0.f, 0.f};
  if (!first) cold = ((const f32x4*)cell)[i];
  f32x4 cnew, hv; s16x4 xb;
#pragma unroll
  for (int c = 0; c < 4; ++c) {
    float ig = sigm(zi[c] + bi[c] + ci_[c]);
    float fg = sigm(zf[c] + bf_[c] + cf[c]);
    float gg = tanhf(zg[c] + bg[c] + cg[c]);
    float og = sigm(zo[c] + bo[c] + co[c]);
    cnew[c] = fg * cold[c] + ig * gg;
    hv[c] = og * tanhf(cnew[c]);
    xb[c] = (short)f2bf(hv[c]);
  }
  ((f32x4*)cell)[i] = cnew;
  ((f32x4*)h)[i] = hv;
  *(s16x4*)&X[(size_t)n * KX + HID + hid] = xb;
}

// ---------------- column sum: S[hid] = sum_n alive[n]*h[n][hid]  (S pre-zeroed)
__global__ void colsum(const float* __restrict__ h, const float* __restrict__ alive,
                       float* __restrict__ S) {
  int hid = blockIdx.x * 256 + threadIdx.x;
  int r0 = blockIdx.y * 128;
  float s = 0.f;
  for (int n = r0; n < r0 + 128; ++n) s += alive[n] * h[(size_t)n * HID + hid];
  atomicAdd(&S[hid], s);
}

// ---------------- comm + inp: X-inp-part = bf16(e + alive_i*(S - alive_i*h)/(nA-1))
__global__ void inp_k(const float* __restrict__ e, const float* __restrict__ h,
                      const float* __restrict__ S, const float* __restrict__ alive,
                      const float* __restrict__ nA, unsigned short* __restrict__ X) {
  int i = blockIdx.x * 256 + threadIdx.x;  // over 1M
  int n = i >> 9;
  int hid = (i & 511) * 4;
  f32x4 ev = ((const f32x4*)e)[i];
  f32x4 hv = ((const f32x4*)h)[i];
  f32x4 Sv = *(const f32x4*)&S[hid];
  float al = alive[n];
  float inv = al / (nA[0] - 1.0f);
  s16x4 xb;
#pragma unroll
  for (int c = 0; c < 4; ++c) {
    float x = ev[c] + (Sv[c] - al * hv[c]) * inv;
    xb[c] = (short)f2bf(x);
  }
  *(s16x4*)&X[(size_t)n * KX + hid] = xb;
}

// ---------------- head: log_softmax(h@act_w^T + act_b) and h@val_w^T + val_b
__global__ __launch_bounds__(64) void head_k(const float* __restrict__ h,
                                             const float* __restrict__ act_w,
                                             const float* __restrict__ act_b,
                                             const float* __restrict__ val_w,
                                             const float* __restrict__ val_b,
                                             float* __restrict__ out) {
  __shared__ float hrow[HID];
  int n = blockIdx.x, t = threadIdx.x;  // 64 threads = 1 wave
  const float* hr = h + (size_t)n * HID;
  for (int k = t; k < HID; k += 64) hrow[k] = hr[k];
  __syncthreads();
  const float* aw = act_w + (size_t)t * HID;
  float acc = act_b[t];
  for (int k = 0; k < HID; k += 4) {
    f32x4 a = *(const f32x4*)&aw[k];
    f32x4 hh = *(const f32x4*)&hrow[k];
    acc += a[0] * hh[0] + a[1] * hh[1] + a[2] * hh[2] + a[3] * hh[3];
  }
  float m = acc;
  for (int off = 32; off; off >>= 1) m = fmaxf(m, __shfl_xor(m, off));
  float ex = expf(acc - m), s = ex;
  for (int off = 32; off; off >>= 1) s += __shfl_xor(s, off);
  out[(size_t)n * ACT + t] = acc - m - logf(s);
  float vp = 0.f;
  for (int k = t; k < HID; k += 64) vp += hrow[k] * val_w[k];
  for (int off = 32; off; off >>= 1) vp += __shfl_xor(vp, off);
  if (t == 0) out[(size_t)N_AG * ACT + n] = vp + val_b[0];
}

extern "C" void kernel_launch(void* const* d_in, const int* in_sizes, int n_in,
                              void* d_out, int out_size, void* d_ws, size_t ws_size,
                              hipStream_t stream) {
  const float* obs   = (const float*)d_in[0];
  const float* alive = (const float*)d_in[1];
  const float* enc_w = (const float*)d_in[2];
  const float* enc_b = (const float*)d_in[3];
  // d_in[4] g_w, d_in[5] g_b: unused — gate = ceil(sigmoid(.)) == 1 identically
  const float* w_ih  = (const float*)d_in[6];
  const float* w_hh  = (const float*)d_in[7];
  const float* b_ih  = (const float*)d_in[8];
  const float* b_hh  = (const float*)d_in[9];
  const float* act_w = (const float*)d_in[10];
  const float* act_b = (const float*)d_in[11];
  const float* val_w = (const float*)d_in[12];
  const float* val_b = (const float*)d_in[13];
  float* out = (float*)d_out;

  char* p = (char*)d_ws;
  unsigned short* Wc   = (unsigned short*)p; p += (size_t)GATES * KX * 2;   // 64 MB
  unsigned short* X    = (unsigned short*)p; p += (size_t)N_AG * KX * 2;    // 16 MB
  unsigned short* obsb = (unsigned short*)p; p += (size_t)N_AG * OBSD * 2;  // 4 MB
  unsigned short* encb = (unsigned short*)p; p += (size_t)HID * OBSD * 2;   // 4 MB
  float* z    = (float*)p; p += (size_t)N_AG * GATES * 4;                   // 64 MB
  float* e    = (float*)p; p += (size_t)N_AG * HID * 4;                     // 16 MB
  float* h    = (float*)p; p += (size_t)N_AG * HID * 4;
  float* cell = (float*)p; p += (size_t)N_AG * HID * 4;
  float* S    = (float*)p; p += 2048 * 4;
  float* nA   = (float*)p; p += 256;

  // per-launch input conversion (ws is re-poisoned every call)
  cvt4<<<(N_AG * OBSD / 4 + 255) / 256, 256, 0, stream>>>(obs, obsb, N_AG * OBSD / 4);
  cvt4<<<(HID * OBSD / 4 + 255) / 256, 256, 0, stream>>>(enc_w, encb, HID * OBSD / 4);
  build_wc<<<(GATES * KX / 4) / 256, 256, 0, stream>>>(w_ih, w_hh, Wc);
  nalive_k<<<1, 256, 0, stream>>>(alive, nA);

  // encoder: e = tanh(obs @ enc_w^T + b) fused into GEMM epilogue; fills X
  gemm_bt<1><<<dim3(HID / 128, N_AG / 128), 256, 0, stream>>>(
      obsb, encb, e, OBSD, OBSD, OBSD, HID, enc_b, X);

  for (int it = 0; it < 3; ++it) {
    if (it > 0) {
      hipMemsetAsync(S, 0, 2048 * 4, stream);
      colsum<<<dim3(HID / 256, 16), 256, 0, stream>>>(h, alive, S);
      inp_k<<<(N_AG * HID / 4) / 256, 256, 0, stream>>>(e, h, S, alive, nA, X);
    }
    // z(2048x8192) = X @ Wc^T ; iter0: h==0 so only K=HID (inp half)
    int K = (it == 0) ? HID : KX;
    gemm_bt<0><<<dim3(GATES / 128, N_AG / 128), 256, 0, stream>>>(
        X, Wc, z, K, KX, KX, GATES, nullptr, nullptr);
    lstm_k<<<(N_AG * HID / 4) / 256, 256, 0, stream>>>(z, b_ih, b_hh, cell, h, X, it == 0);
  }

  head_k<<<N_AG, 64, 0, stream>>>(h, act_w, act_b, val_w, val_b, out);
}